// Round 1
// 81.127 us; speedup vs baseline: 1.0154x; 1.0154x over previous
//
#include <hip/hip_runtime.h>
#include <float.h>

// Chamfer distance, B=8, N1=N2=4096, 3-D fp32 points.
// dist(a,b) = |a|^2 + |b|^2 - 2 a.b ; min over the other set, both directions.
// Packed dual-FP32 (v_pk_fma_f32) inner loop: per 2 B-points x 1 A-point:
// 3 pk_fma + 1 min3 = 2.0 VALU instr/pair (was 2.5 with two scalar mins).

typedef float v2f __attribute__((ext_vector_type(2)));

#define NBATCH 8
#define NPTS   4096
#define BLK    256
#define PTS    16                 // A-points per thread
#define NCHUNK 32
#define CHUNK  (NPTS / NCHUNK)    // 128 B-points staged per block
#define PAIRS  (CHUNK / 2)        // 64 packed pairs

__global__ __launch_bounds__(BLK)
void chamfer_min_kernel(const float* __restrict__ p1,
                        const float* __restrict__ p2,
                        unsigned int* __restrict__ mins /* [2][8][4096] uint bits */)
{
    // Packed-pair B staging: sXY[p] = {x0,x1,y0,y1}, sZW[p] = {z0,z1,w0,w1}
    // (w = |b|^2). float2 slices of these quads are register-adjacent.
    __shared__ float4 sXY[PAIRS];
    __shared__ float4 sZW[PAIRS];

    int bid   = blockIdx.x;
    int chunk = bid & (NCHUNK - 1);  bid >>= 5;   // 32 chunks
    int b     = bid & (NBATCH - 1);  bid >>= 3;   // 8 batches
    int dir   = bid;                              // 0 or 1

    const float* A    = dir ? p2 : p1;
    const float* Bpts = dir ? p1 : p2;
    int tid = threadIdx.x;

    if (tid < PAIRS) {
        const float* s = Bpts + ((size_t)b * NPTS + chunk * CHUNK + 2 * tid) * 3;
        float x0 = s[0], y0 = s[1], z0 = s[2];
        float x1 = s[3], y1 = s[4], z1 = s[5];
        sXY[tid] = make_float4(x0, x1, y0, y1);
        sZW[tid] = make_float4(z0, z1,
                               x0 * x0 + y0 * y0 + z0 * z0,
                               x1 * x1 + y1 * y1 + z1 * z1);
    }

    // Per-thread A-points, pre-scaled by -2, duplicated into packed pairs.
    v2f  m2x[PTS], m2y[PTS], m2z[PTS];
    float n1[PTS], best[PTS];
#pragma unroll
    for (int k = 0; k < PTS; ++k) {
        const float* s = A + ((size_t)b * NPTS + tid + k * BLK) * 3;
        float x = s[0], y = s[1], z = s[2];
        float mx = -2.0f * x, my = -2.0f * y, mz = -2.0f * z;
        m2x[k] = (v2f){mx, mx};
        m2y[k] = (v2f){my, my};
        m2z[k] = (v2f){mz, mz};
        n1[k]  = x * x + y * y + z * z;
        best[k] = FLT_MAX;
    }
    __syncthreads();

    // Min-scan: per packed B-pair, per A-point: 3 pk_fma + 1 min3.
#pragma unroll 2
    for (int p = 0; p < PAIRS; ++p) {
        float4 xy = sXY[p];
        float4 zw = sZW[p];
        v2f qx = (v2f){xy.x, xy.y};
        v2f qy = (v2f){xy.z, xy.w};
        v2f qz = (v2f){zw.x, zw.y};
        v2f qw = (v2f){zw.z, zw.w};
#pragma unroll
        for (int k = 0; k < PTS; ++k) {
            v2f t = __builtin_elementwise_fma(m2x[k], qx, qw);
            t = __builtin_elementwise_fma(m2y[k], qy, t);
            t = __builtin_elementwise_fma(m2z[k], qz, t);
            // nested fminf -> v_min3_f32 (both halves feed the same A-point min)
            best[k] = fminf(fminf(best[k], t.x), t.y);
        }
    }

    // Publish per-A-point chunk-min via uint atomicMin (valid for d >= 0).
    unsigned int* marr = mins + ((size_t)dir * NBATCH + b) * NPTS + tid;
#pragma unroll
    for (int k = 0; k < PTS; ++k) {
        float d = fmaxf(best[k] + n1[k], 0.0f);
        atomicMin(&marr[k * BLK], __float_as_uint(d));
    }
}

// Stage 1: 64 blocks x 256 threads, one float4 per thread = 65536 mins exactly.
// Spread across 64 CUs so the cross-XCD latency of reading the atomic results
// is hidden by TLP (the old single-block reduce was latency-bound on one CU).
__global__ __launch_bounds__(256)
void chamfer_reduce1(const float* __restrict__ mins, float* __restrict__ partials)
{
    __shared__ float wave_sums[4];
    int idx = blockIdx.x * 256 + threadIdx.x;
    float4 v = ((const float4*)mins)[idx];
    float s = (v.x + v.y) + (v.z + v.w);
#pragma unroll
    for (int off = 32; off > 0; off >>= 1)
        s += __shfl_down(s, off, 64);
    if ((threadIdx.x & 63) == 0) wave_sums[threadIdx.x >> 6] = s;
    __syncthreads();
    if (threadIdx.x == 0)
        partials[blockIdx.x] = (wave_sums[0] + wave_sums[1]) + (wave_sums[2] + wave_sums[3]);
}

// Stage 2: one wave sums the 64 block partials; loss = sum / (8*4096).
__global__ __launch_bounds__(64)
void chamfer_reduce2(const float* __restrict__ partials, float* __restrict__ out)
{
    float s = partials[threadIdx.x];
#pragma unroll
    for (int off = 32; off > 0; off >>= 1)
        s += __shfl_down(s, off, 64);
    if (threadIdx.x == 0) out[0] = s / (float)(NBATCH * NPTS);
}

extern "C" void kernel_launch(void* const* d_in, const int* in_sizes, int n_in,
                              void* d_out, int out_size, void* d_ws, size_t ws_size,
                              hipStream_t stream) {
    const float* p1 = (const float*)d_in[0];
    const float* p2 = (const float*)d_in[1];
    float* out = (float*)d_out;
    unsigned int* mins = (unsigned int*)d_ws;
    float* partials = (float*)d_ws + 2 * NBATCH * NPTS;  // 64 floats after mins

    // Init mins to 0xFFFFFFFF (uint max; > any positive float bit pattern).
    hipMemsetAsync(d_ws, 0xFF, (size_t)2 * NBATCH * NPTS * sizeof(unsigned int), stream);

    int nblocks = 2 * NBATCH * NCHUNK;  // 512
    chamfer_min_kernel<<<nblocks, BLK, 0, stream>>>(p1, p2, mins);
    chamfer_reduce1<<<64, 256, 0, stream>>>((const float*)d_ws, partials);
    chamfer_reduce2<<<1, 64, 0, stream>>>(partials, out);
}

// Round 2
// 80.617 us; speedup vs baseline: 1.0219x; 1.0063x over previous
//
#include <hip/hip_runtime.h>
#include <float.h>

// Chamfer distance, B=8, N1=N2=4096, 3-D fp32 points.
// dist(a,b) = |a|^2 + |b|^2 - 2 a.b ; min over the other set, both directions.
// Packed dual-FP32 (v_pk_fma_f32) inner loop: per 2 B-points x 1 A-point:
// 3 pk_fma + 1 min3 = 2.0 VALU instr/pair.
//
// R2 change: NO ATOMICS. Each chunk-block writes its local per-A-point min to a
// private slot mins2[(dir,b)][chunk][4096] with plain dwordx4 stores (8 MiB);
// reduce1 min-reduces over the chunk axis (coalesced float4, stride 16 KiB) and
// sums in the same pass. Removes 2.1M device-scope atomicMin (the suspected
// ~15-20us serialization tail) and the 256 KiB memset.

typedef float v2f __attribute__((ext_vector_type(2)));

#define NBATCH 8
#define NPTS   4096
#define BLK    256
#define PTS    16                 // A-points per thread (4 groups of 4 consecutive)
#define NCHUNK 32
#define CHUNK  (NPTS / NCHUNK)    // 128 B-points staged per block
#define PAIRS  (CHUNK / 2)        // 64 packed pairs
#define NDB    (2 * NBATCH)       // 16 (dir,b) pairs

__global__ __launch_bounds__(BLK)
void chamfer_min_kernel(const float* __restrict__ p1,
                        const float* __restrict__ p2,
                        float* __restrict__ mins2 /* [16][32][4096] */)
{
    // Packed-pair B staging: sXY[p] = {x0,x1,y0,y1}, sZW[p] = {z0,z1,w0,w1}
    // (w = |b|^2). float2 slices of these quads are register-adjacent.
    __shared__ float4 sXY[PAIRS];
    __shared__ float4 sZW[PAIRS];

    int bid   = blockIdx.x;
    int chunk = bid & (NCHUNK - 1);  bid >>= 5;   // 32 chunks
    int b     = bid & (NBATCH - 1);  bid >>= 3;   // 8 batches
    int dir   = bid;                              // 0 or 1

    const float* A    = dir ? p2 : p1;
    const float* Bpts = dir ? p1 : p2;
    int tid = threadIdx.x;

    if (tid < PAIRS) {
        const float* s = Bpts + ((size_t)b * NPTS + chunk * CHUNK + 2 * tid) * 3;
        float x0 = s[0], y0 = s[1], z0 = s[2];
        float x1 = s[3], y1 = s[4], z1 = s[5];
        sXY[tid] = make_float4(x0, x1, y0, y1);
        sZW[tid] = make_float4(z0, z1,
                               x0 * x0 + y0 * y0 + z0 * z0,
                               x1 * x1 + y1 * y1 + z1 * z1);
    }

    // Per-thread A-points: 4 groups of 4 CONSECUTIVE points (a = k*1024 + 4*tid + j)
    // so prologue loads are 3x float4 and epilogue store is 1x float4 per group.
    v2f  m2x[PTS], m2y[PTS], m2z[PTS];
    float n1[PTS], best[PTS];
#pragma unroll
    for (int k = 0; k < 4; ++k) {
        const float* s = A + ((size_t)b * NPTS + k * 1024 + 4 * tid) * 3;
        float4 f0 = ((const float4*)s)[0];
        float4 f1 = ((const float4*)s)[1];
        float4 f2 = ((const float4*)s)[2];
        float px[4] = {f0.x, f0.w, f1.z, f2.y};
        float py[4] = {f0.y, f1.x, f1.w, f2.z};
        float pz[4] = {f0.z, f1.y, f2.x, f2.w};
#pragma unroll
        for (int j = 0; j < 4; ++j) {
            int kk = k * 4 + j;
            float x = px[j], y = py[j], z = pz[j];
            float mx = -2.0f * x, my = -2.0f * y, mz = -2.0f * z;
            m2x[kk] = (v2f){mx, mx};
            m2y[kk] = (v2f){my, my};
            m2z[kk] = (v2f){mz, mz};
            n1[kk]  = x * x + y * y + z * z;
            best[kk] = FLT_MAX;
        }
    }
    __syncthreads();

    // Min-scan: per packed B-pair, per A-point: 3 pk_fma + 1 min3.
#pragma unroll 2
    for (int p = 0; p < PAIRS; ++p) {
        float4 xy = sXY[p];
        float4 zw = sZW[p];
        v2f qx = (v2f){xy.x, xy.y};
        v2f qy = (v2f){xy.z, xy.w};
        v2f qz = (v2f){zw.x, zw.y};
        v2f qw = (v2f){zw.z, zw.w};
#pragma unroll
        for (int k = 0; k < PTS; ++k) {
            v2f t = __builtin_elementwise_fma(m2x[k], qx, qw);
            t = __builtin_elementwise_fma(m2y[k], qy, t);
            t = __builtin_elementwise_fma(m2z[k], qz, t);
            // nested fminf -> v_min3_f32 (both halves feed the same A-point min)
            best[k] = fminf(fminf(best[k], t.x), t.y);
        }
    }

    // Publish per-A-point chunk-local min with plain float4 stores (no atomics).
    float* slot = mins2 + (((size_t)(dir * NBATCH + b) * NCHUNK + chunk) * NPTS) + 4 * tid;
#pragma unroll
    for (int k = 0; k < 4; ++k) {
        float4 dv;
        dv.x = fmaxf(best[k * 4 + 0] + n1[k * 4 + 0], 0.0f);
        dv.y = fmaxf(best[k * 4 + 1] + n1[k * 4 + 1], 0.0f);
        dv.z = fmaxf(best[k * 4 + 2] + n1[k * 4 + 2], 0.0f);
        dv.w = fmaxf(best[k * 4 + 3] + n1[k * 4 + 3], 0.0f);
        ((float4*)(slot + (size_t)k * 1024))[0] = dv;
    }
}

// Stage 1: 64 blocks = (16 (dir,b) x 4 quarters). Each thread owns 4 A-slots
// (one float4), min-reduces over the 32 chunk slices (coalesced float4 loads,
// 1 KiB per wave-instruction), then the block sums its 1024 final mins.
__global__ __launch_bounds__(256)
void chamfer_reduce1(const float* __restrict__ mins2, float* __restrict__ partials)
{
    __shared__ float wave_sums[4];
    int db = blockIdx.x >> 2;
    int q  = blockIdx.x & 3;
    const float4* base = (const float4*)mins2 + ((size_t)db * (NCHUNK * NPTS / 4) + q * 256) + threadIdx.x;

    float4 m = base[0];
#pragma unroll
    for (int c = 1; c < NCHUNK; ++c) {
        float4 v = base[(size_t)c * (NPTS / 4)];
        m.x = fminf(m.x, v.x);
        m.y = fminf(m.y, v.y);
        m.z = fminf(m.z, v.z);
        m.w = fminf(m.w, v.w);
    }
    float s = (m.x + m.y) + (m.z + m.w);
#pragma unroll
    for (int off = 32; off > 0; off >>= 1)
        s += __shfl_down(s, off, 64);
    if ((threadIdx.x & 63) == 0) wave_sums[threadIdx.x >> 6] = s;
    __syncthreads();
    if (threadIdx.x == 0)
        partials[blockIdx.x] = (wave_sums[0] + wave_sums[1]) + (wave_sums[2] + wave_sums[3]);
}

// Stage 2: one wave sums the 64 block partials; loss = sum / (8*4096).
__global__ __launch_bounds__(64)
void chamfer_reduce2(const float* __restrict__ partials, float* __restrict__ out)
{
    float s = partials[threadIdx.x];
#pragma unroll
    for (int off = 32; off > 0; off >>= 1)
        s += __shfl_down(s, off, 64);
    if (threadIdx.x == 0) out[0] = s / (float)(NBATCH * NPTS);
}

extern "C" void kernel_launch(void* const* d_in, const int* in_sizes, int n_in,
                              void* d_out, int out_size, void* d_ws, size_t ws_size,
                              hipStream_t stream) {
    const float* p1 = (const float*)d_in[0];
    const float* p2 = (const float*)d_in[1];
    float* out = (float*)d_out;
    float* mins2 = (float*)d_ws;                                  // 16*32*4096 floats = 8 MiB
    float* partials = mins2 + (size_t)NDB * NCHUNK * NPTS;        // 64 floats

    int nblocks = NDB * NCHUNK;  // 512
    chamfer_min_kernel<<<nblocks, BLK, 0, stream>>>(p1, p2, mins2);
    chamfer_reduce1<<<64, 256, 0, stream>>>(mins2, partials);
    chamfer_reduce2<<<1, 64, 0, stream>>>(partials, out);
}